// Round 1
// baseline (219.142 us; speedup 1.0000x reference)
//
#include <hip/hip_runtime.h>
#include <hip/hip_fp16.h>

#define N_NODES 100000
#define IN_F 128
#define NF 16      // HEADS * OUT_C
#define HEADS 8
#define NEG_SLOPE 0.2f
#define LOG2E 1.44269504f

#define RB 128          // nodes per bin (power of 2)
#define LOG_RB 7
#define NB 782          // ceil(100000/128)
#define SBITS 17        // src id bits (100000 < 2^17)
#define SMASK ((1u << SBITS) - 1)
#define BIN_C 4096      // edges per binning block (8/thread @512)
#define CAPB 4608       // per-bin capacity: mean 4092 + 8 sigma; = 9*512 exactly

// Node record rec[n]: 16 halves = 32B, layout [h0c0,h0c1,h1c0,h1c1,...].
// Table = 3.2 MB -> L2-resident per XCD.

// ---------------------------------------------------------------------------
// phase1: h = x@W. 8 lanes per node, each lane computes an output PAIR.
// ---------------------------------------------------------------------------
__device__ __forceinline__ void phase1_body(
    int pb, const float* __restrict__ x, const float* __restrict__ W,
    __half* __restrict__ rec, float* Ws)
{
    int t = threadIdx.x;
    for (int i = t; i < IN_F * NF; i += 512) Ws[i] = W[i];
    __syncthreads();

    int tid  = pb * 512 + t;
    int node = tid >> 3;
    int j    = tid & 7;         // output-pair index (cols 2j, 2j+1)
    if (node >= N_NODES) return;

    const float4* xr4 = (const float4*)(x + (size_t)node * IN_F);
    const float2* Wp  = (const float2*)Ws;   // pair (k, j) at index k*8 + j

    float a0 = 0.f, b0 = 0.f, a1 = 0.f, b1 = 0.f;
    #pragma unroll 8
    for (int k4 = 0; k4 < IN_F / 4; ++k4) {
        float4 xv = xr4[k4];
        float2 w0 = Wp[(4 * k4 + 0) * 8 + j];
        float2 w1 = Wp[(4 * k4 + 1) * 8 + j];
        float2 w2 = Wp[(4 * k4 + 2) * 8 + j];
        float2 w3 = Wp[(4 * k4 + 3) * 8 + j];
        a0 = fmaf(xv.x, w0.x, a0); b0 = fmaf(xv.x, w0.y, b0);
        a1 = fmaf(xv.y, w1.x, a1); b1 = fmaf(xv.y, w1.y, b1);
        a0 = fmaf(xv.z, w2.x, a0); b0 = fmaf(xv.z, w2.y, b0);
        a1 = fmaf(xv.w, w3.x, a1); b1 = fmaf(xv.w, w3.y, b1);
    }
    __half2 hv = __floats2half2_rn(a0 + a1, b0 + b1);
    *(__half2*)(rec + (size_t)node * NF + 2 * j) = hv;
}

// ---------------------------------------------------------------------------
// Fused kernel: every 3rd block is bin-role (SB total), rest phase1 (PB).
// Bin role: load 4096 edges into registers; LDS counting-sort by dst bin
// (782 bins of 128 nodes); reserve per-(block,bin) ranges with one global
// atomic each; write packed records (d_local<<17 | src).
// ---------------------------------------------------------------------------
__global__ __launch_bounds__(512) void fused_p1_bin(
    const int* __restrict__ ei, int* __restrict__ bin_cursor,
    unsigned* __restrict__ bins,
    const float* __restrict__ x, const float* __restrict__ W,
    __half* __restrict__ rec, int E, int SB)
{
    __shared__ union {
        struct {
            unsigned staging[BIN_C];        // 16 KB
            unsigned short bin16[BIN_C];    // 8 KB
            int hist[NB], offs[NB], cur[NB], gbase[NB]; // 12.5 KB
            int wsum[8], woff[8];
        } b;
        float Ws[IN_F * NF];
    } sm;

    int idx = blockIdx.x;
    bool is_bin = (idx % 3 == 0) && (idx / 3 < SB);
    if (!is_bin) {
        int cb = (idx + 2) / 3; if (cb > SB) cb = SB;
        phase1_body(idx - cb, x, W, rec, sm.Ws);
        return;
    }

    int t = threadIdx.x;
    int base = (idx / 3) * BIN_C;
    int n_valid = E - base;
    if (n_valid > BIN_C) n_valid = BIN_C;
    if (n_valid < 0) n_valid = 0;

    // load this block's edges once, coalesced, into registers
    int es[8], ed[8];
    #pragma unroll
    for (int k = 0; k < 8; ++k) {
        int i = t + 512 * k;
        bool v = i < n_valid;
        es[k] = v ? ei[base + i] : 0;
        ed[k] = v ? ei[E + base + i] : -1;
    }

    for (int i = t; i < NB; i += 512) sm.b.hist[i] = 0;
    __syncthreads();

    // A: histogram of dst bins (from registers)
    #pragma unroll
    for (int k = 0; k < 8; ++k)
        if (ed[k] >= 0) atomicAdd(&sm.b.hist[ed[k] >> LOG_RB], 1);
    __syncthreads();

    // B: block-wide exclusive scan of hist (2 bins/thread) + global reserve
    int b0 = 2 * t, b1 = b0 + 1;
    int h0 = (b0 < NB) ? sm.b.hist[b0] : 0;
    int h1 = (b1 < NB) ? sm.b.hist[b1] : 0;
    int sum = h0 + h1;
    int lane = t & 63, wid = t >> 6;
    int v = sum;
    #pragma unroll
    for (int o = 1; o < 64; o <<= 1) {
        int u = __shfl_up(v, o);
        if (lane >= o) v += u;
    }
    if (lane == 63) sm.b.wsum[wid] = v;
    __syncthreads();
    if (t == 0) { int r = 0; for (int w = 0; w < 8; ++w) { sm.b.woff[w] = r; r += sm.b.wsum[w]; } }
    __syncthreads();
    int run = sm.b.woff[wid] + v - sum;
    if (b0 < NB) { sm.b.offs[b0] = run; sm.b.cur[b0] = run; }
    if (b1 < NB) { sm.b.offs[b1] = run + h0; sm.b.cur[b1] = run + h0; }
    __syncthreads();
    if (b0 < NB) sm.b.gbase[b0] = h0 ? atomicAdd(&bin_cursor[b0], h0) : 0;
    if (b1 < NB) sm.b.gbase[b1] = h1 ? atomicAdd(&bin_cursor[b1], h1) : 0;
    __syncthreads();

    // C: counting-sort into LDS staging (from registers)
    #pragma unroll
    for (int k = 0; k < 8; ++k) {
        if (ed[k] >= 0) {
            int bb = ed[k] >> LOG_RB;
            int slot = atomicAdd(&sm.b.cur[bb], 1);
            sm.b.staging[slot] = ((unsigned)(ed[k] & (RB - 1)) << SBITS) | (unsigned)es[k];
            sm.b.bin16[slot] = (unsigned short)bb;
        }
    }
    __syncthreads();

    // D: write-out (runs of ~5 consecutive slots per bin)
    for (int i = t; i < n_valid; i += 512) {
        int bb = sm.b.bin16[i];
        int pos = sm.b.gbase[bb] + (i - sm.b.offs[bb]);
        if (pos < CAPB) bins[(size_t)bb * CAPB + pos] = sm.b.staging[i];
    }
}

__device__ __forceinline__ float2 h2f2(unsigned u) {
    __half2 h = *reinterpret_cast<__half2*>(&u);
    return __half22float2(h);
}

// ---------------------------------------------------------------------------
// Accum: ONE 512-thread block (8 waves) per 128-node bin (782 blocks -> all
// blocks resident, 4/CU, wave skew 4:3 instead of 2:1). Segment cached in
// STATICALLY-indexed rc[9] (registers, not scratch). LDS counting-sort into
// per-node order; wave-per-node gather: lane = e_off(0..15) x part(0..3);
// each lane loads ONE b64 (2 heads) of the 32B rec row -> 16 edges in flight,
// 2-way unrolled (32 in flight). Shuffle reduce over e_off (masks 4..32),
// self-loop folded, normalize + bias + FC, reduce over part (masks 1,2).
// ---------------------------------------------------------------------------
__global__ __launch_bounds__(512, 8) void accum8_kernel(
    const unsigned* __restrict__ bins, const int* __restrict__ bin_cursor,
    const __half* __restrict__ rec,
    const float* __restrict__ att_src, const float* __restrict__ att_dst,
    const float* __restrict__ bias, const float* __restrict__ Wfc,
    const float* __restrict__ bfc, float* __restrict__ out)
{
    __shared__ unsigned staging[CAPB];          // 18 KB
    __shared__ int hist[RB], offs[RB + 1], cur[RB];

    int t = threadIdx.x;
    int b = blockIdx.x;
    int node0 = b * RB;

    if (t < RB) hist[t] = 0;
    __syncthreads();

    int cnt = bin_cursor[b];
    if (cnt > CAPB) cnt = CAPB;
    const unsigned* seg = bins + (size_t)b * CAPB;

    // cache segment in registers — STATIC indexing (9*512 == CAPB)
    unsigned rc[9];
    #pragma unroll
    for (int k = 0; k < 9; ++k) {
        int i = t + 512 * k;
        rc[k] = (i < cnt) ? seg[i] : 0xFFFFFFFFu;
    }

    // A: per-node histogram
    #pragma unroll
    for (int k = 0; k < 9; ++k)
        if (rc[k] != 0xFFFFFFFFu) atomicAdd(&hist[rc[k] >> SBITS], 1);
    __syncthreads();

    // B: scan of 128 counters by wave 0 (lane l owns nodes 2l, 2l+1)
    if (t < 64) {
        int h0 = hist[2 * t], h1 = hist[2 * t + 1];
        int v = h0 + h1;
        int inc = v;
        #pragma unroll
        for (int o = 1; o < 64; o <<= 1) {
            int u = __shfl_up(inc, o);
            if (t >= o) inc += u;
        }
        int ex = inc - v;
        offs[2 * t] = ex;     cur[2 * t] = ex;     ex += h0;
        offs[2 * t + 1] = ex; cur[2 * t + 1] = ex;
        if (t == 63) offs[RB] = inc;
    }
    __syncthreads();

    // C: sort src ids into per-node order in LDS
    #pragma unroll
    for (int k = 0; k < 9; ++k) {
        unsigned r = rc[k];
        if (r != 0xFFFFFFFFu) {
            int slot = atomicAdd(&cur[r >> SBITS], 1);
            staging[slot] = r & SMASK;
        }
    }
    __syncthreads();

    // D: wave-per-node gather (8 waves x 16 nodes each)
    int wv = t >> 6, lane = t & 63;
    int part  = lane & 3;    // head pair: heads 2*part, 2*part+1
    int e_off = lane >> 2;   // 0..15

    // lane constants (LOG2E folded into att coefficients)
    float asA0 = att_src[4 * part + 0] * LOG2E, asA1 = att_src[4 * part + 1] * LOG2E;
    float asB0 = att_src[4 * part + 2] * LOG2E, asB1 = att_src[4 * part + 3] * LOG2E;
    float adA0 = att_dst[4 * part + 0] * LOG2E, adA1 = att_dst[4 * part + 1] * LOG2E;
    float adB0 = att_dst[4 * part + 2] * LOG2E, adB1 = att_dst[4 * part + 3] * LOG2E;
    float bA0 = bias[4 * part + 0], bA1 = bias[4 * part + 1];
    float bB0 = bias[4 * part + 2], bB1 = bias[4 * part + 3];
    float wA00 = Wfc[(4 * part + 0) * 2 + 0], wA01 = Wfc[(4 * part + 0) * 2 + 1];
    float wA10 = Wfc[(4 * part + 1) * 2 + 0], wA11 = Wfc[(4 * part + 1) * 2 + 1];
    float wB00 = Wfc[(4 * part + 2) * 2 + 0], wB01 = Wfc[(4 * part + 2) * 2 + 1];
    float wB10 = Wfc[(4 * part + 3) * 2 + 0], wB11 = Wfc[(4 * part + 3) * 2 + 1];
    float c0 = bfc[0], c1 = bfc[1];

    const uint2* recq = (const uint2*)rec;   // 8B units; row n at index n*4

    for (int k = 0; k < RB / 8; ++k) {
        int ln = wv + 8 * k;            // wave-uniform local node
        int n = node0 + ln;
        if (n >= N_NODES) break;
        int st  = offs[ln];
        int deg = offs[ln + 1] - st;

        // this node's own h for this head pair (also the self-loop source)
        uint2 hq = recq[n * 4 + part];
        float2 fnA = h2f2(hq.x), fnB = h2f2(hq.y);
        float adstA = fmaf(adA0, fnA.x, adA1 * fnA.y);
        float adstB = fmaf(adB0, fnB.x, adB1 * fnB.y);

        float denA = 0.f, n0A = 0.f, n1A = 0.f;
        float denB = 0.f, n0B = 0.f, n1B = 0.f;

        int i = e_off;
        for (; i + 16 < deg; i += 32) {
            int sX = staging[st + i];
            int sY = staging[st + i + 16];
            uint2 rX = recq[sX * 4 + part];
            uint2 rY = recq[sY * 4 + part];
            {
                float2 xA = h2f2(rX.x), xB = h2f2(rX.y);
                float lA = fmaf(asA0, xA.x, fmaf(asA1, xA.y, adstA));
                lA = lA > 0.f ? lA : NEG_SLOPE * lA;
                float pA = exp2f(lA);
                denA += pA; n0A = fmaf(pA, xA.x, n0A); n1A = fmaf(pA, xA.y, n1A);
                float lB = fmaf(asB0, xB.x, fmaf(asB1, xB.y, adstB));
                lB = lB > 0.f ? lB : NEG_SLOPE * lB;
                float pB = exp2f(lB);
                denB += pB; n0B = fmaf(pB, xB.x, n0B); n1B = fmaf(pB, xB.y, n1B);
            }
            {
                float2 xA = h2f2(rY.x), xB = h2f2(rY.y);
                float lA = fmaf(asA0, xA.x, fmaf(asA1, xA.y, adstA));
                lA = lA > 0.f ? lA : NEG_SLOPE * lA;
                float pA = exp2f(lA);
                denA += pA; n0A = fmaf(pA, xA.x, n0A); n1A = fmaf(pA, xA.y, n1A);
                float lB = fmaf(asB0, xB.x, fmaf(asB1, xB.y, adstB));
                lB = lB > 0.f ? lB : NEG_SLOPE * lB;
                float pB = exp2f(lB);
                denB += pB; n0B = fmaf(pB, xB.x, n0B); n1B = fmaf(pB, xB.y, n1B);
            }
        }
        if (i < deg) {
            int s = staging[st + i];
            uint2 rX = recq[s * 4 + part];
            float2 xA = h2f2(rX.x), xB = h2f2(rX.y);
            float lA = fmaf(asA0, xA.x, fmaf(asA1, xA.y, adstA));
            lA = lA > 0.f ? lA : NEG_SLOPE * lA;
            float pA = exp2f(lA);
            denA += pA; n0A = fmaf(pA, xA.x, n0A); n1A = fmaf(pA, xA.y, n1A);
            float lB = fmaf(asB0, xB.x, fmaf(asB1, xB.y, adstB));
            lB = lB > 0.f ? lB : NEG_SLOPE * lB;
            float pB = exp2f(lB);
            denB += pB; n0B = fmaf(pB, xB.x, n0B); n1B = fmaf(pB, xB.y, n1B);
        }

        // reduce over the 16 e_off lanes (stride-4 butterfly)
        #pragma unroll
        for (int m = 4; m < 64; m <<= 1) {
            denA += __shfl_xor(denA, m);
            n0A  += __shfl_xor(n0A, m);
            n1A  += __shfl_xor(n1A, m);
            denB += __shfl_xor(denB, m);
            n0B  += __shfl_xor(n0B, m);
            n1B  += __shfl_xor(n1B, m);
        }
        // self-loop folded analytically (identical in all lanes post-reduce)
        {
            float lA = fmaf(asA0, fnA.x, fmaf(asA1, fnA.y, adstA));
            lA = lA > 0.f ? lA : NEG_SLOPE * lA;
            float pA = exp2f(lA);
            denA += pA; n0A = fmaf(pA, fnA.x, n0A); n1A = fmaf(pA, fnA.y, n1A);
            float lB = fmaf(asB0, fnB.x, fmaf(asB1, fnB.y, adstB));
            lB = lB > 0.f ? lB : NEG_SLOPE * lB;
            float pB = exp2f(lB);
            denB += pB; n0B = fmaf(pB, fnB.x, n0B); n1B = fmaf(pB, fnB.y, n1B);
        }
        // normalize + bias + FC (both heads of this lane), sum over parts
        float iA = 1.f / denA, iB = 1.f / denB;
        float gA0 = fmaf(n0A, iA, bA0), gA1 = fmaf(n1A, iA, bA1);
        float gB0 = fmaf(n0B, iB, bB0), gB1 = fmaf(n1B, iB, bB1);
        float o0 = gA0 * wA00 + gA1 * wA10 + gB0 * wB00 + gB1 * wB10;
        float o1 = gA0 * wA01 + gA1 * wA11 + gB0 * wB01 + gB1 * wB11;
        o0 += __shfl_xor(o0, 1); o0 += __shfl_xor(o0, 2);
        o1 += __shfl_xor(o1, 1); o1 += __shfl_xor(o1, 2);
        if (lane == 0) {
            float2 res = { o0 + c0, o1 + c1 };
            *(float2*)(out + (size_t)n * 2) = res;
        }
    }
}

// ---------------------------------------------------------------------------
extern "C" void kernel_launch(void* const* d_in, const int* in_sizes, int n_in,
                              void* d_out, int out_size, void* d_ws, size_t ws_size,
                              hipStream_t stream)
{
    const float* x       = (const float*)d_in[0];
    const int*   ei      = (const int*)d_in[1];   // [2, E]
    const float* W       = (const float*)d_in[3];
    const float* att_src = (const float*)d_in[4];
    const float* att_dst = (const float*)d_in[5];
    const float* bias    = (const float*)d_in[6];
    const float* Wfc     = (const float*)d_in[7];
    const float* bfc     = (const float*)d_in[8];
    float*       out     = (float*)d_out;

    const int E  = in_sizes[1] / 2;
    const int SB = (E + BIN_C - 1) / BIN_C;            // bin-role blocks (782)
    const int PB = (N_NODES * 8 + 511) / 512;          // phase1-role blocks (1563)

    // ws layout: rec f16[N*16] (3.2MB) | bin_cursor i32[NB] | (4KB align) |
    //            bins u32[NB*CAPB] (~14.4MB)
    __half* rec        = (__half*)d_ws;
    int*    bin_cursor = (int*)((char*)d_ws + (size_t)N_NODES * NF * 2);
    size_t  bins_off   = (((size_t)((char*)bin_cursor - (char*)d_ws)) + NB * 4 + 4095) & ~(size_t)4095;
    unsigned* bins     = (unsigned*)((char*)d_ws + bins_off);

    hipMemsetAsync(bin_cursor, 0, NB * sizeof(int), stream);

    fused_p1_bin<<<SB + PB, 512, 0, stream>>>(
        ei, bin_cursor, bins, x, W, rec, E, SB);
    accum8_kernel<<<NB, 512, 0, stream>>>(
        bins, bin_cursor, rec, att_src, att_dst, bias, Wfc, bfc, out);
}

// Round 3
// 202.085 us; speedup vs baseline: 1.0844x; 1.0844x over previous
//
#include <hip/hip_runtime.h>
#include <hip/hip_fp16.h>

#define N_NODES 100000
#define IN_F 128
#define NF 16      // HEADS * OUT_C
#define HEADS 8
#define NEG_SLOPE 0.2f
#define LOG2E 1.44269504f

#define RB 256          // nodes per bin (power of 2)
#define LOG_RB 8
#define NB 391          // ceil(100000/256)
#define SBITS 17        // src id bits (100000 < 2^17)
#define SMASK ((1u << SBITS) - 1)
#define BIN_C 4096      // edges per binning block (8/thread @512)
#define CAPB 9216       // per-bin capacity: mean 8184 + ~11 sigma; = 9*1024 exactly

// Node record rec[n]: 16 halves = 32B. Table = 3.2 MB -> L2-resident per XCD.

// ---------------------------------------------------------------------------
// phase1: h = x@W. 8 lanes per node, each lane computes an output PAIR.
// ---------------------------------------------------------------------------
__device__ __forceinline__ void phase1_body(
    int pb, const float* __restrict__ x, const float* __restrict__ W,
    __half* __restrict__ rec, float* Ws)
{
    int t = threadIdx.x;
    for (int i = t; i < IN_F * NF; i += 512) Ws[i] = W[i];
    __syncthreads();

    int tid  = pb * 512 + t;
    int node = tid >> 3;
    int j    = tid & 7;         // output-pair index (cols 2j, 2j+1)
    if (node >= N_NODES) return;

    const float4* xr4 = (const float4*)(x + (size_t)node * IN_F);
    const float2* Wp  = (const float2*)Ws;   // pair (k, j) at index k*8 + j

    float a0 = 0.f, b0 = 0.f, a1 = 0.f, b1 = 0.f;
    #pragma unroll 8
    for (int k4 = 0; k4 < IN_F / 4; ++k4) {
        float4 xv = xr4[k4];
        float2 w0 = Wp[(4 * k4 + 0) * 8 + j];
        float2 w1 = Wp[(4 * k4 + 1) * 8 + j];
        float2 w2 = Wp[(4 * k4 + 2) * 8 + j];
        float2 w3 = Wp[(4 * k4 + 3) * 8 + j];
        a0 = fmaf(xv.x, w0.x, a0); b0 = fmaf(xv.x, w0.y, b0);
        a1 = fmaf(xv.y, w1.x, a1); b1 = fmaf(xv.y, w1.y, b1);
        a0 = fmaf(xv.z, w2.x, a0); b0 = fmaf(xv.z, w2.y, b0);
        a1 = fmaf(xv.w, w3.x, a1); b1 = fmaf(xv.w, w3.y, b1);
    }
    __half2 hv = __floats2half2_rn(a0 + a1, b0 + b1);
    *(__half2*)(rec + (size_t)node * NF + 2 * j) = hv;
}

// ---------------------------------------------------------------------------
// Fused kernel: every 3rd block is bin-role (SB total), rest phase1 (PB).
// Bin role: load 4096 edges into registers; LDS counting-sort by dst bin
// (391 bins of 256 nodes); reserve per-(block,bin) ranges with one global
// atomic each; write packed records (d_local<<17 | src) coalesced.
// ---------------------------------------------------------------------------
__global__ __launch_bounds__(512) void fused_p1_bin(
    const int* __restrict__ ei, int* __restrict__ bin_cursor,
    unsigned* __restrict__ bins,
    const float* __restrict__ x, const float* __restrict__ W,
    __half* __restrict__ rec, int E, int SB)
{
    __shared__ union {
        struct {
            unsigned staging[BIN_C];        // 16 KB
            unsigned short bin16[BIN_C];    // 8 KB
            int hist[NB], offs[NB], cur[NB], gbase[NB]; // 6.3 KB
            int wsum[8], woff[8];
        } b;
        float Ws[IN_F * NF];
    } sm;

    int idx = blockIdx.x;
    bool is_bin = (idx % 3 == 0) && (idx / 3 < SB);
    if (!is_bin) {
        int cb = (idx + 2) / 3; if (cb > SB) cb = SB;
        phase1_body(idx - cb, x, W, rec, sm.Ws);
        return;
    }

    int t = threadIdx.x;
    int base = (idx / 3) * BIN_C;
    int n_valid = E - base;
    if (n_valid > BIN_C) n_valid = BIN_C;
    if (n_valid < 0) n_valid = 0;

    // load this block's edges once, coalesced, into registers
    int es[8], ed[8];
    #pragma unroll
    for (int k = 0; k < 8; ++k) {
        int i = t + 512 * k;
        bool v = i < n_valid;
        es[k] = v ? ei[base + i] : 0;
        ed[k] = v ? ei[E + base + i] : -1;
    }

    if (t < NB) sm.b.hist[t] = 0;
    __syncthreads();

    // A: histogram of dst bins (from registers)
    #pragma unroll
    for (int k = 0; k < 8; ++k)
        if (ed[k] >= 0) atomicAdd(&sm.b.hist[ed[k] >> LOG_RB], 1);
    __syncthreads();

    // B: block-wide exclusive scan of hist (1 bin/thread) + global reserve
    int sum = (t < NB) ? sm.b.hist[t] : 0;
    int lane = t & 63, wid = t >> 6;
    int v = sum;
    #pragma unroll
    for (int o = 1; o < 64; o <<= 1) {
        int u = __shfl_up(v, o);
        if (lane >= o) v += u;
    }
    if (lane == 63) sm.b.wsum[wid] = v;
    __syncthreads();
    if (t == 0) { int r = 0; for (int w = 0; w < 8; ++w) { sm.b.woff[w] = r; r += sm.b.wsum[w]; } }
    __syncthreads();
    int run = sm.b.woff[wid] + v - sum;
    if (t < NB) { sm.b.offs[t] = run; sm.b.cur[t] = run; }
    __syncthreads();
    if (t < NB)
        sm.b.gbase[t] = sm.b.hist[t] ? atomicAdd(&bin_cursor[t], sm.b.hist[t]) : 0;
    __syncthreads();

    // C: counting-sort into LDS staging (from registers)
    #pragma unroll
    for (int k = 0; k < 8; ++k) {
        if (ed[k] >= 0) {
            int b = ed[k] >> LOG_RB;
            int slot = atomicAdd(&sm.b.cur[b], 1);
            sm.b.staging[slot] = ((unsigned)(ed[k] & (RB - 1)) << SBITS) | (unsigned)es[k];
            sm.b.bin16[slot] = (unsigned short)b;
        }
    }
    __syncthreads();

    // D: coalesced write-out (runs of ~10.5 consecutive slots per bin)
    for (int i = t; i < n_valid; i += 512) {
        int b = sm.b.bin16[i];
        int pos = sm.b.gbase[b] + (i - sm.b.offs[b]);
        if (pos < CAPB) bins[(size_t)b * CAPB + pos] = sm.b.staging[i];
    }
}

// ---------------------------------------------------------------------------
// Accum: ONE 1024-thread block (16 waves) per 256-node bin (391 blocks).
// Segment cached in STATIC rc[9] (9*1024 == CAPB). LDS counting-sort into
// per-node order. D-phase gather is DEEP-PREFETCHED: per node, issue ALL
// staging reads (4 or 8 LDS b32), then ALL rec loads (4 or 8 x 4B in flight,
// MLP 4-8), then compute fully unrolled with per-batch predication.
// CRITICAL: prefetched src ids are clamped to < N_NODES (reads can land in
// the uninitialized pad past cnt; unclamped ids index past the rec table and
// pull NaN bit patterns — fmaf(0, NaN, acc) poisons the accumulator).
// ---------------------------------------------------------------------------
__global__ __launch_bounds__(1024) void accum9_kernel(
    const unsigned* __restrict__ bins, const int* __restrict__ bin_cursor,
    const __half* __restrict__ rec,
    const float* __restrict__ att_src, const float* __restrict__ att_dst,
    const float* __restrict__ bias, const float* __restrict__ Wfc,
    const float* __restrict__ bfc, float* __restrict__ out)
{
    __shared__ unsigned staging[CAPB + 64];     // +64 pad: batch reads may run past cnt
    __shared__ int hist[RB], offs[RB + 1], cur[RB];

    int t = threadIdx.x;
    int b = blockIdx.x;
    int node0 = b * RB;

    if (t < RB) hist[t] = 0;
    __syncthreads();

    int cnt = bin_cursor[b];
    if (cnt > CAPB) cnt = CAPB;
    const unsigned* seg = bins + (size_t)b * CAPB;

    // cache segment in registers — STATIC indexing (9*1024 == CAPB)
    unsigned rc[9];
    #pragma unroll
    for (int k = 0; k < 9; ++k) {
        int i = t + 1024 * k;
        rc[k] = (i < cnt) ? seg[i] : 0xFFFFFFFFu;
    }

    // A: per-node histogram
    #pragma unroll
    for (int k = 0; k < 9; ++k)
        if (rc[k] != 0xFFFFFFFFu) atomicAdd(&hist[rc[k] >> SBITS], 1);
    __syncthreads();

    // B: scan of 256 counters by wave 0 (lane l owns nodes 4l..4l+3)
    if (t < 64) {
        int h0 = hist[4 * t], h1 = hist[4 * t + 1];
        int h2 = hist[4 * t + 2], h3 = hist[4 * t + 3];
        int v = h0 + h1 + h2 + h3;
        int inc = v;
        #pragma unroll
        for (int o = 1; o < 64; o <<= 1) {
            int u = __shfl_up(inc, o);
            if (t >= o) inc += u;
        }
        int ex = inc - v;
        offs[4 * t] = ex;     cur[4 * t] = ex;     ex += h0;
        offs[4 * t + 1] = ex; cur[4 * t + 1] = ex; ex += h1;
        offs[4 * t + 2] = ex; cur[4 * t + 2] = ex; ex += h2;
        offs[4 * t + 3] = ex; cur[4 * t + 3] = ex;
        if (t == 63) offs[RB] = inc;
    }
    __syncthreads();

    // C: sort src ids into per-node order in LDS
    #pragma unroll
    for (int k = 0; k < 9; ++k) {
        unsigned r = rc[k];
        if (r != 0xFFFFFFFFu) {
            int slot = atomicAdd(&cur[r >> SBITS], 1);
            staging[slot] = r & SMASK;
        }
    }
    __syncthreads();

    // D: wave-per-node gather (16 waves x 16 nodes each), deep prefetch
    int wv = t >> 6, lane = t & 63;
    int h_id = lane & 7, e_off = lane >> 3;

    // lane constants: att coefficients (LOG2E folded), FC weights, biases
    float as0 = att_src[2 * h_id] * LOG2E, as1 = att_src[2 * h_id + 1] * LOG2E;
    float ad0 = att_dst[2 * h_id] * LOG2E, ad1 = att_dst[2 * h_id + 1] * LOG2E;
    float b0 = bias[2 * h_id], b1 = bias[2 * h_id + 1];
    float w00 = Wfc[(2 * h_id) * 2 + 0],     w01 = Wfc[(2 * h_id) * 2 + 1];
    float w10 = Wfc[(2 * h_id + 1) * 2 + 0], w11 = Wfc[(2 * h_id + 1) * 2 + 1];
    float c0 = bfc[0], c1 = bfc[1];

    const __half2* recp = (const __half2*)rec;   // row n at index n*8 + h_id

    // clamp prefetched id into the rec table (pad reads -> node 0, predicated off)
    #define CLAMP(s) ((s) < (unsigned)N_NODES ? (s) : 0u)
    // per-edge compute: convert, logit, leaky-relu, exp2 (predicated), accum
    #define EDGE(rh, pred) { \
        float h0_ = __half2float((rh).x), h1_ = __half2float((rh).y); \
        float l_ = fmaf(as0, h0_, fmaf(as1, h1_, adst_h)); \
        l_ = l_ > 0.f ? l_ : NEG_SLOPE * l_; \
        float p_ = (pred) ? exp2f(l_) : 0.f; \
        den += p_; num0 = fmaf(p_, h0_, num0); num1 = fmaf(p_, h1_, num1); }

    for (int k = 0; k < RB / 16; ++k) {
        int ln = wv + 16 * k;           // wave-uniform local node
        int n = node0 + ln;
        if (n >= N_NODES) break;
        int st  = offs[ln];
        int deg = offs[ln + 1] - st;

        // this node's own h pair for this head (also the self-loop source)
        __half2 hn = recp[(size_t)n * 8 + h_id];
        float hn0 = __half2float(hn.x), hn1 = __half2float(hn.y);
        float adst_h = fmaf(ad0, hn0, ad1 * hn1);

        float den = 0.f, num0 = 0.f, num1 = 0.f;

        // tier 1: batches 0..3 (covers deg <= 32). All staging reads issued
        // together, then all rec loads together (MLP 4).
        int i0 = st + e_off;
        unsigned s0 = CLAMP(staging[i0]      & SMASK);
        unsigned s1 = CLAMP(staging[i0 + 8]  & SMASK);
        unsigned s2 = CLAMP(staging[i0 + 16] & SMASK);
        unsigned s3 = CLAMP(staging[i0 + 24] & SMASK);
        __half2 r0 = recp[(size_t)s0 * 8 + h_id];
        __half2 r1 = recp[(size_t)s1 * 8 + h_id];
        __half2 r2 = recp[(size_t)s2 * 8 + h_id];
        __half2 r3 = recp[(size_t)s3 * 8 + h_id];
        EDGE(r0, e_off      < deg);
        EDGE(r1, e_off + 8  < deg);
        EDGE(r2, e_off + 16 < deg);
        EDGE(r3, e_off + 24 < deg);

        // tier 2: batches 4..7 (deg 33..64), wave-uniform branch
        if (deg > 32) {
            unsigned s4 = CLAMP(staging[i0 + 32] & SMASK);
            unsigned s5 = CLAMP(staging[i0 + 40] & SMASK);
            unsigned s6 = CLAMP(staging[i0 + 48] & SMASK);
            unsigned s7 = CLAMP(staging[i0 + 56] & SMASK);
            __half2 r4 = recp[(size_t)s4 * 8 + h_id];
            __half2 r5 = recp[(size_t)s5 * 8 + h_id];
            __half2 r6 = recp[(size_t)s6 * 8 + h_id];
            __half2 r7 = recp[(size_t)s7 * 8 + h_id];
            EDGE(r4, e_off + 32 < deg);
            EDGE(r5, e_off + 40 < deg);
            EDGE(r6, e_off + 48 < deg);
            EDGE(r7, e_off + 56 < deg);
            // rare tail: deg > 64 (reads only genuinely valid entries)
            for (int i = 64 + e_off; i < deg; i += 8) {
                unsigned s = staging[st + i] & SMASK;
                __half2 r = recp[(size_t)s * 8 + h_id];
                EDGE(r, true);
            }
        }

        // reduce over the 8 e_off lanes
        #pragma unroll
        for (int m = 8; m < 64; m <<= 1) {
            den  += __shfl_xor(den,  m);
            num0 += __shfl_xor(num0, m);
            num1 += __shfl_xor(num1, m);
        }
        // self-loop folded analytically
        {
            float l = fmaf(as0, hn0, fmaf(as1, hn1, adst_h));
            l = l > 0.f ? l : NEG_SLOPE * l;
            float p = exp2f(l);
            den += p;
            num0 = fmaf(p, hn0, num0);
            num1 = fmaf(p, hn1, num1);
        }
        // normalize + bias + FC, sum over heads
        float inv = 1.f / den;
        float g0 = fmaf(num0, inv, b0);
        float g1 = fmaf(num1, inv, b1);
        float o0 = g0 * w00 + g1 * w10;
        float o1 = g0 * w01 + g1 * w11;
        #pragma unroll
        for (int m = 1; m < 8; m <<= 1) {
            o0 += __shfl_xor(o0, m);
            o1 += __shfl_xor(o1, m);
        }
        if (lane == 0) {
            float2 res = { o0 + c0, o1 + c1 };
            *(float2*)(out + (size_t)n * 2) = res;
        }
    }
    #undef EDGE
    #undef CLAMP
}

// ---------------------------------------------------------------------------
extern "C" void kernel_launch(void* const* d_in, const int* in_sizes, int n_in,
                              void* d_out, int out_size, void* d_ws, size_t ws_size,
                              hipStream_t stream)
{
    const float* x       = (const float*)d_in[0];
    const int*   ei      = (const int*)d_in[1];   // [2, E]
    const float* W       = (const float*)d_in[3];
    const float* att_src = (const float*)d_in[4];
    const float* att_dst = (const float*)d_in[5];
    const float* bias    = (const float*)d_in[6];
    const float* Wfc     = (const float*)d_in[7];
    const float* bfc     = (const float*)d_in[8];
    float*       out     = (float*)d_out;

    const int E  = in_sizes[1] / 2;
    const int SB = (E + BIN_C - 1) / BIN_C;            // bin-role blocks (782)
    const int PB = (N_NODES * 8 + 511) / 512;          // phase1-role blocks (1563)

    // ws layout: rec f16[N*16] (3.2MB) | bin_cursor i32[NB] | (4KB align) |
    //            bins u32[NB*CAPB] (~14.4MB)
    __half* rec        = (__half*)d_ws;
    int*    bin_cursor = (int*)((char*)d_ws + (size_t)N_NODES * NF * 2);
    size_t  bins_off   = (((size_t)((char*)bin_cursor - (char*)d_ws)) + NB * 4 + 4095) & ~(size_t)4095;
    unsigned* bins     = (unsigned*)((char*)d_ws + bins_off);

    hipMemsetAsync(bin_cursor, 0, NB * sizeof(int), stream);

    fused_p1_bin<<<SB + PB, 512, 0, stream>>>(
        ei, bin_cursor, bins, x, W, rec, E, SB);
    accum9_kernel<<<NB, 1024, 0, stream>>>(
        bins, bin_cursor, rec, att_src, att_dst, bias, Wfc, bfc, out);
}

// Round 4
// 195.513 us; speedup vs baseline: 1.1209x; 1.0336x over previous
//
#include <hip/hip_runtime.h>
#include <hip/hip_fp16.h>

#define N_NODES 100000
#define IN_F 128
#define NF 16      // HEADS * OUT_C
#define HEADS 8
#define NEG_SLOPE 0.2f
#define LOG2E 1.44269504f

#define RB 256          // nodes per bin (power of 2)
#define LOG_RB 8
#define NB 391          // ceil(100000/256)
#define SBITS 17        // src id bits (100000 < 2^17)
#define SMASK ((1u << SBITS) - 1)
#define BIN_C 4096      // edges per binning block (8/thread @512)
#define CAPB 9216       // per-bin capacity: mean 8184 + ~11 sigma; = 9*1024 exactly

// Node record rec[n]: 16 halves = 32B. Table = 3.2 MB -> L2-resident per XCD.

// ---------------------------------------------------------------------------
// phase1: h = x@W. 8 lanes per node, each lane computes an output PAIR.
// ---------------------------------------------------------------------------
__device__ __forceinline__ void phase1_body(
    int pb, const float* __restrict__ x, const float* __restrict__ W,
    __half* __restrict__ rec, float* Ws)
{
    int t = threadIdx.x;
    for (int i = t; i < IN_F * NF; i += 512) Ws[i] = W[i];
    __syncthreads();

    int tid  = pb * 512 + t;
    int node = tid >> 3;
    int j    = tid & 7;         // output-pair index (cols 2j, 2j+1)
    if (node >= N_NODES) return;

    const float4* xr4 = (const float4*)(x + (size_t)node * IN_F);
    const float2* Wp  = (const float2*)Ws;   // pair (k, j) at index k*8 + j

    float a0 = 0.f, b0 = 0.f, a1 = 0.f, b1 = 0.f;
    #pragma unroll 8
    for (int k4 = 0; k4 < IN_F / 4; ++k4) {
        float4 xv = xr4[k4];
        float2 w0 = Wp[(4 * k4 + 0) * 8 + j];
        float2 w1 = Wp[(4 * k4 + 1) * 8 + j];
        float2 w2 = Wp[(4 * k4 + 2) * 8 + j];
        float2 w3 = Wp[(4 * k4 + 3) * 8 + j];
        a0 = fmaf(xv.x, w0.x, a0); b0 = fmaf(xv.x, w0.y, b0);
        a1 = fmaf(xv.y, w1.x, a1); b1 = fmaf(xv.y, w1.y, b1);
        a0 = fmaf(xv.z, w2.x, a0); b0 = fmaf(xv.z, w2.y, b0);
        a1 = fmaf(xv.w, w3.x, a1); b1 = fmaf(xv.w, w3.y, b1);
    }
    __half2 hv = __floats2half2_rn(a0 + a1, b0 + b1);
    *(__half2*)(rec + (size_t)node * NF + 2 * j) = hv;
}

// ---------------------------------------------------------------------------
// Fused kernel: every 3rd block is bin-role (SB total), rest phase1 (PB).
// ---------------------------------------------------------------------------
__global__ __launch_bounds__(512) void fused_p1_bin(
    const int* __restrict__ ei, int* __restrict__ bin_cursor,
    unsigned* __restrict__ bins,
    const float* __restrict__ x, const float* __restrict__ W,
    __half* __restrict__ rec, int E, int SB)
{
    __shared__ union {
        struct {
            unsigned staging[BIN_C];        // 16 KB
            unsigned short bin16[BIN_C];    // 8 KB
            int hist[NB], offs[NB], cur[NB], gbase[NB]; // 6.3 KB
            int wsum[8], woff[8];
        } b;
        float Ws[IN_F * NF];
    } sm;

    int idx = blockIdx.x;
    bool is_bin = (idx % 3 == 0) && (idx / 3 < SB);
    if (!is_bin) {
        int cb = (idx + 2) / 3; if (cb > SB) cb = SB;
        phase1_body(idx - cb, x, W, rec, sm.Ws);
        return;
    }

    int t = threadIdx.x;
    int base = (idx / 3) * BIN_C;
    int n_valid = E - base;
    if (n_valid > BIN_C) n_valid = BIN_C;
    if (n_valid < 0) n_valid = 0;

    // load this block's edges once, coalesced, into registers
    int es[8], ed[8];
    #pragma unroll
    for (int k = 0; k < 8; ++k) {
        int i = t + 512 * k;
        bool v = i < n_valid;
        es[k] = v ? ei[base + i] : 0;
        ed[k] = v ? ei[E + base + i] : -1;
    }

    if (t < NB) sm.b.hist[t] = 0;
    __syncthreads();

    // A: histogram of dst bins (from registers)
    #pragma unroll
    for (int k = 0; k < 8; ++k)
        if (ed[k] >= 0) atomicAdd(&sm.b.hist[ed[k] >> LOG_RB], 1);
    __syncthreads();

    // B: block-wide exclusive scan of hist (1 bin/thread) + global reserve
    int sum = (t < NB) ? sm.b.hist[t] : 0;
    int lane = t & 63, wid = t >> 6;
    int v = sum;
    #pragma unroll
    for (int o = 1; o < 64; o <<= 1) {
        int u = __shfl_up(v, o);
        if (lane >= o) v += u;
    }
    if (lane == 63) sm.b.wsum[wid] = v;
    __syncthreads();
    if (t == 0) { int r = 0; for (int w = 0; w < 8; ++w) { sm.b.woff[w] = r; r += sm.b.wsum[w]; } }
    __syncthreads();
    int run = sm.b.woff[wid] + v - sum;
    if (t < NB) { sm.b.offs[t] = run; sm.b.cur[t] = run; }
    __syncthreads();
    if (t < NB)
        sm.b.gbase[t] = sm.b.hist[t] ? atomicAdd(&bin_cursor[t], sm.b.hist[t]) : 0;
    __syncthreads();

    // C: counting-sort into LDS staging (from registers)
    #pragma unroll
    for (int k = 0; k < 8; ++k) {
        if (ed[k] >= 0) {
            int b = ed[k] >> LOG_RB;
            int slot = atomicAdd(&sm.b.cur[b], 1);
            sm.b.staging[slot] = ((unsigned)(ed[k] & (RB - 1)) << SBITS) | (unsigned)es[k];
            sm.b.bin16[slot] = (unsigned short)b;
        }
    }
    __syncthreads();

    // D: coalesced write-out (runs of ~10.5 consecutive slots per bin)
    for (int i = t; i < n_valid; i += 512) {
        int b = sm.b.bin16[i];
        int pos = sm.b.gbase[b] + (i - sm.b.offs[b]);
        if (pos < CAPB) bins[(size_t)b * CAPB + pos] = sm.b.staging[i];
    }
}

// ---------------------------------------------------------------------------
// Accum: ONE 1024-thread block per 256-node bin (391 blocks). Phases A-C as
// before (rc[9] static register cache, LDS counting-sort). D-phase processes
// nodes in PAIRS (cross-node software pipeline, T14): node B's staging reads,
// own-row load and 4 rec loads are issued BEFORE node A's compute, so each
// node's ~90 VALU ops cover the other's ~200cy L2 latency. Tails (deg>32,
// ~46% of nodes) interleave A and B in one rolled loop for the same reason.
// Prefetched ids CLAMPed to < N_NODES (pad garbage -> row 0, predicated off).
// ---------------------------------------------------------------------------
__global__ __launch_bounds__(1024, 8) void accum10_kernel(
    const unsigned* __restrict__ bins, const int* __restrict__ bin_cursor,
    const __half* __restrict__ rec,
    const float* __restrict__ att_src, const float* __restrict__ att_dst,
    const float* __restrict__ bias, const float* __restrict__ Wfc,
    const float* __restrict__ bfc, float* __restrict__ out)
{
    __shared__ unsigned staging[CAPB + 64];     // +64 pad: batch reads may run past cnt
    __shared__ int hist[RB], offs[RB + 1], cur[RB];

    int t = threadIdx.x;
    int b = blockIdx.x;
    int node0 = b * RB;

    if (t < RB) hist[t] = 0;
    __syncthreads();

    int cnt = bin_cursor[b];
    if (cnt > CAPB) cnt = CAPB;
    const unsigned* seg = bins + (size_t)b * CAPB;

    // cache segment in registers — STATIC indexing (9*1024 == CAPB)
    unsigned rc[9];
    #pragma unroll
    for (int k = 0; k < 9; ++k) {
        int i = t + 1024 * k;
        rc[k] = (i < cnt) ? seg[i] : 0xFFFFFFFFu;
    }

    // A: per-node histogram
    #pragma unroll
    for (int k = 0; k < 9; ++k)
        if (rc[k] != 0xFFFFFFFFu) atomicAdd(&hist[rc[k] >> SBITS], 1);
    __syncthreads();

    // B: scan of 256 counters by wave 0 (lane l owns nodes 4l..4l+3)
    if (t < 64) {
        int h0 = hist[4 * t], h1 = hist[4 * t + 1];
        int h2 = hist[4 * t + 2], h3 = hist[4 * t + 3];
        int v = h0 + h1 + h2 + h3;
        int inc = v;
        #pragma unroll
        for (int o = 1; o < 64; o <<= 1) {
            int u = __shfl_up(inc, o);
            if (t >= o) inc += u;
        }
        int ex = inc - v;
        offs[4 * t] = ex;     cur[4 * t] = ex;     ex += h0;
        offs[4 * t + 1] = ex; cur[4 * t + 1] = ex; ex += h1;
        offs[4 * t + 2] = ex; cur[4 * t + 2] = ex; ex += h2;
        offs[4 * t + 3] = ex; cur[4 * t + 3] = ex;
        if (t == 63) offs[RB] = inc;
    }
    __syncthreads();

    // C: sort src ids into per-node order in LDS
    #pragma unroll
    for (int k = 0; k < 9; ++k) {
        unsigned r = rc[k];
        if (r != 0xFFFFFFFFu) {
            int slot = atomicAdd(&cur[r >> SBITS], 1);
            staging[slot] = r & SMASK;
        }
    }
    __syncthreads();

    // D: wave-per-node gather, node-PAIR pipelined
    int wv = t >> 6, lane = t & 63;
    int h_id = lane & 7, e_off = lane >> 3;

    // lane constants: att coefficients (LOG2E folded), FC weights, biases
    float as0 = att_src[2 * h_id] * LOG2E, as1 = att_src[2 * h_id + 1] * LOG2E;
    float ad0 = att_dst[2 * h_id] * LOG2E, ad1 = att_dst[2 * h_id + 1] * LOG2E;
    float b0 = bias[2 * h_id], b1 = bias[2 * h_id + 1];
    float w00 = Wfc[(2 * h_id) * 2 + 0],     w01 = Wfc[(2 * h_id) * 2 + 1];
    float w10 = Wfc[(2 * h_id + 1) * 2 + 0], w11 = Wfc[(2 * h_id + 1) * 2 + 1];
    float c0 = bfc[0], c1 = bfc[1];

    const __half2* recp = (const __half2*)rec;   // row n at index n*8 + h_id

    // clamp prefetched id into the rec table (pad garbage -> node 0)
    #define CLAMP(s) ((s) < (unsigned)N_NODES ? (s) : 0u)
    #define EDGE(rh, pred, adst, den, num0, num1) { \
        float h0_ = __half2float((rh).x), h1_ = __half2float((rh).y); \
        float l_ = fmaf(as0, h0_, fmaf(as1, h1_, adst)); \
        l_ = l_ > 0.f ? l_ : NEG_SLOPE * l_; \
        float p_ = (pred) ? exp2f(l_) : 0.f; \
        den += p_; num0 = fmaf(p_, h0_, num0); num1 = fmaf(p_, h1_, num1); }

    for (int k = 0; k < RB / 16; k += 2) {
        int lnA = wv + 16 * k, lnB = lnA + 16;
        int nA = node0 + lnA, nB = node0 + lnB;
        if (nA >= N_NODES) break;
        bool hasB = (nB < N_NODES);

        int stA = offs[lnA], degA = offs[lnA + 1] - stA;
        int stB = offs[lnB], degB = hasB ? (offs[lnB + 1] - stB) : 0;

        // ---- issue phase: ALL of A's and B's loads before any compute ----
        int iA = stA + e_off, iB = stB + e_off;
        unsigned sA0 = CLAMP(staging[iA]);
        unsigned sA1 = CLAMP(staging[iA + 8]);
        unsigned sA2 = CLAMP(staging[iA + 16]);
        unsigned sA3 = CLAMP(staging[iA + 24]);
        unsigned sB0 = CLAMP(staging[iB]);
        unsigned sB1 = CLAMP(staging[iB + 8]);
        unsigned sB2 = CLAMP(staging[iB + 16]);
        unsigned sB3 = CLAMP(staging[iB + 24]);

        __half2 hnA = recp[(size_t)nA * 8 + h_id];
        __half2 hnB = recp[(size_t)(hasB ? nB : nA) * 8 + h_id];

        __half2 rA0 = recp[(size_t)sA0 * 8 + h_id];
        __half2 rA1 = recp[(size_t)sA1 * 8 + h_id];
        __half2 rA2 = recp[(size_t)sA2 * 8 + h_id];
        __half2 rA3 = recp[(size_t)sA3 * 8 + h_id];
        __half2 rB0 = recp[(size_t)sB0 * 8 + h_id];
        __half2 rB1 = recp[(size_t)sB1 * 8 + h_id];
        __half2 rB2 = recp[(size_t)sB2 * 8 + h_id];
        __half2 rB3 = recp[(size_t)sB3 * 8 + h_id];

        // ---- node A compute (covers B's loads in flight) ----
        float hnA0 = __half2float(hnA.x), hnA1 = __half2float(hnA.y);
        float adstA = fmaf(ad0, hnA0, ad1 * hnA1);
        float denA = 0.f, n0A = 0.f, n1A = 0.f;
        EDGE(rA0, e_off      < degA, adstA, denA, n0A, n1A);
        EDGE(rA1, e_off + 8  < degA, adstA, denA, n0A, n1A);
        EDGE(rA2, e_off + 16 < degA, adstA, denA, n0A, n1A);
        EDGE(rA3, e_off + 24 < degA, adstA, denA, n0A, n1A);

        // ---- node B compute ----
        float hnB0 = __half2float(hnB.x), hnB1 = __half2float(hnB.y);
        float adstB = fmaf(ad0, hnB0, ad1 * hnB1);
        float denB = 0.f, n0B = 0.f, n1B = 0.f;
        EDGE(rB0, e_off      < degB, adstB, denB, n0B, n1B);
        EDGE(rB1, e_off + 8  < degB, adstB, denB, n0B, n1B);
        EDGE(rB2, e_off + 16 < degB, adstB, denB, n0B, n1B);
        EDGE(rB3, e_off + 24 < degB, adstB, denB, n0B, n1B);

        // ---- interleaved tails (deg > 32): A and B loads alternate ----
        if (degA > 32 || degB > 32) {
            for (int i = 32 + e_off; i < degA || i < degB; i += 8) {
                bool vA = i < degA, vB = i < degB;
                unsigned sa = vA ? staging[stA + i] : 0u;   // valid entries already masked
                unsigned sb = vB ? staging[stB + i] : 0u;
                __half2 ra = recp[(size_t)sa * 8 + h_id];
                __half2 rb = recp[(size_t)sb * 8 + h_id];
                EDGE(ra, vA, adstA, denA, n0A, n1A);
                EDGE(rb, vB, adstB, denB, n0B, n1B);
            }
        }

        // ---- reductions (A and B independent -> ILP) ----
        #pragma unroll
        for (int m = 8; m < 64; m <<= 1) {
            denA += __shfl_xor(denA, m);
            n0A  += __shfl_xor(n0A, m);
            n1A  += __shfl_xor(n1A, m);
            denB += __shfl_xor(denB, m);
            n0B  += __shfl_xor(n0B, m);
            n1B  += __shfl_xor(n1B, m);
        }
        // self-loops folded analytically
        {
            float l = fmaf(as0, hnA0, fmaf(as1, hnA1, adstA));
            l = l > 0.f ? l : NEG_SLOPE * l;
            float p = exp2f(l);
            denA += p; n0A = fmaf(p, hnA0, n0A); n1A = fmaf(p, hnA1, n1A);
        }
        {
            float l = fmaf(as0, hnB0, fmaf(as1, hnB1, adstB));
            l = l > 0.f ? l : NEG_SLOPE * l;
            float p = exp2f(l);
            denB += p; n0B = fmaf(p, hnB0, n0B); n1B = fmaf(p, hnB1, n1B);
        }
        // normalize + bias + FC, sum over heads — node A
        {
            float inv = 1.f / denA;
            float g0 = fmaf(n0A, inv, b0);
            float g1 = fmaf(n1A, inv, b1);
            float o0 = g0 * w00 + g1 * w10;
            float o1 = g0 * w01 + g1 * w11;
            #pragma unroll
            for (int m = 1; m < 8; m <<= 1) {
                o0 += __shfl_xor(o0, m);
                o1 += __shfl_xor(o1, m);
            }
            if (lane == 0) {
                float2 res = { o0 + c0, o1 + c1 };
                *(float2*)(out + (size_t)nA * 2) = res;
            }
        }
        // node B
        if (hasB) {
            float inv = 1.f / denB;
            float g0 = fmaf(n0B, inv, b0);
            float g1 = fmaf(n1B, inv, b1);
            float o0 = g0 * w00 + g1 * w10;
            float o1 = g0 * w01 + g1 * w11;
            #pragma unroll
            for (int m = 1; m < 8; m <<= 1) {
                o0 += __shfl_xor(o0, m);
                o1 += __shfl_xor(o1, m);
            }
            if (lane == 0) {
                float2 res = { o0 + c0, o1 + c1 };
                *(float2*)(out + (size_t)nB * 2) = res;
            }
        }
    }
    #undef EDGE
    #undef CLAMP
}

// ---------------------------------------------------------------------------
extern "C" void kernel_launch(void* const* d_in, const int* in_sizes, int n_in,
                              void* d_out, int out_size, void* d_ws, size_t ws_size,
                              hipStream_t stream)
{
    const float* x       = (const float*)d_in[0];
    const int*   ei      = (const int*)d_in[1];   // [2, E]
    const float* W       = (const float*)d_in[3];
    const float* att_src = (const float*)d_in[4];
    const float* att_dst = (const float*)d_in[5];
    const float* bias    = (const float*)d_in[6];
    const float* Wfc     = (const float*)d_in[7];
    const float* bfc     = (const float*)d_in[8];
    float*       out     = (float*)d_out;

    const int E  = in_sizes[1] / 2;
    const int SB = (E + BIN_C - 1) / BIN_C;            // bin-role blocks (782)
    const int PB = (N_NODES * 8 + 511) / 512;          // phase1-role blocks (1563)

    // ws layout: rec f16[N*16] (3.2MB) | bin_cursor i32[NB] | (4KB align) |
    //            bins u32[NB*CAPB] (~14.4MB)
    __half* rec        = (__half*)d_ws;
    int*    bin_cursor = (int*)((char*)d_ws + (size_t)N_NODES * NF * 2);
    size_t  bins_off   = (((size_t)((char*)bin_cursor - (char*)d_ws)) + NB * 4 + 4095) & ~(size_t)4095;
    unsigned* bins     = (unsigned*)((char*)d_ws + bins_off);

    hipMemsetAsync(bin_cursor, 0, NB * sizeof(int), stream);

    fused_p1_bin<<<SB + PB, 512, 0, stream>>>(
        ei, bin_cursor, bins, x, W, rec, E, SB);
    accum10_kernel<<<NB, 1024, 0, stream>>>(
        bins, bin_cursor, rec, att_src, att_dst, bias, Wfc, bfc, out);
}